// Round 5
// baseline (117.721 us; speedup 1.0000x reference)
//
#include <hip/hip_runtime.h>

#define LN_EPS 1e-5f

constexpr int Bn = 4, Nn = 256, Dn = 256, Hn = 256;

// ws layout (floats):
//   aA    @ 0        (1024*256)
//   bB    @ 262144   (1024*256)
//   rC    @ 524288   (1024)   -- atomic accumulators r[b,h], zeroed in gemm
//   Cpart @ 525312   (1024)   -- per-pair-block C partials (no contention)
//   rel   @ 526336   (1024)

// ---------------------------------------------------------------------------
// Kernel 1: aA[m,h] = x[m,:]@Wg[:D,h] + bg[h]  (half=0)
//           bB[m,h] = x[m,:]@Wg[D:,h]          (half=1)
// Block: 4-row m-tile, 512 threads = (h4 in [0,64), dc in [0,8)).
// float4 W loads (1KB/wave coalesced), 8-deep unroll. Block (0,0) zeroes rC.
// ---------------------------------------------------------------------------
__global__ __launch_bounds__(512) void gemm_ab_kernel(
    const float* __restrict__ x, const float* __restrict__ Wg,
    const float* __restrict__ bg, float* __restrict__ aA,
    float* __restrict__ bB, float* __restrict__ rC)
{
    int mt = blockIdx.x;     // 0..255
    int half = blockIdx.y;   // 0 -> a, 1 -> b
    int m0 = mt * 4;
    int t = threadIdx.x;

    if (mt == 0 && half == 0) {
        for (int k = t; k < 1024; k += 512) rC[k] = 0.0f;
    }

    __shared__ float xs[4][256];
    __shared__ float accP[8][4][256];

    if (t < 256)
        reinterpret_cast<float4*>(&xs[0][0])[t] =
            reinterpret_cast<const float4*>(x + m0 * Dn)[t];
    __syncthreads();

    int h4 = t & 63;
    int dc = t >> 6;         // wave-uniform
    const float* Wp = Wg + (half ? Dn * Hn : 0) + h4 * 4;

    float4 acc[4];
#pragma unroll
    for (int m = 0; m < 4; ++m) acc[m] = make_float4(0.f, 0.f, 0.f, 0.f);

#pragma unroll 8
    for (int dd = 0; dd < 32; ++dd) {
        int d = dc * 32 + dd;
        float4 w = *reinterpret_cast<const float4*>(Wp + d * Hn);
#pragma unroll
        for (int m = 0; m < 4; ++m) {
            float xv = xs[m][d];
            acc[m].x = fmaf(xv, w.x, acc[m].x);
            acc[m].y = fmaf(xv, w.y, acc[m].y);
            acc[m].z = fmaf(xv, w.z, acc[m].z);
            acc[m].w = fmaf(xv, w.w, acc[m].w);
        }
    }
#pragma unroll
    for (int m = 0; m < 4; ++m)
        *reinterpret_cast<float4*>(&accP[dc][m][h4 * 4]) = acc[m];
    __syncthreads();

    int h = t & 255;
    int mh = t >> 8;
    float binit = half ? 0.0f : bg[h];
    float* outp = half ? bB : aA;
#pragma unroll
    for (int mi = 0; mi < 2; ++mi) {
        int m = mh * 2 + mi;
        float v = binit;
#pragma unroll
        for (int c = 0; c < 8; ++c) v += accP[c][m][h];
        outp[(m0 + m) * Hn + h] = v;
    }
}

// ---------------------------------------------------------------------------
// Kernel 2: fused pair block, single pass over bB, j-SPLIT for occupancy.
// Block = (b, 2 i-rows, j-half of 128), 512 threads, grid 1024 (4 blocks/CU).
// Per j-tile (32 rows):
//   stage: thread (jg=t>>4, p=t&15) loads row jg's 16 scattered float4,
//          computes LN stats from the SAME registers, ds_writes to Bs,
//          prefetches next tile, 16-lane shuffle reduce -> invL[i][jg].
//   phase2: thread (h4=t&63, c=t>>6) accumulates its 4 j's from LDS.
// End: LDS combine, 1 atomic/h; Cpart[block] (no contention).
// ---------------------------------------------------------------------------
__global__ __launch_bounds__(512, 4) void pair_kernel(
    const float* __restrict__ aA, const float* __restrict__ bB,
    float* __restrict__ rC, float* __restrict__ Cpart)
{
    const int b   = blockIdx.x >> 8;
    const int r8  = blockIdx.x & 255;
    const int i0  = (r8 >> 1) * 2;
    const int jbase = (r8 & 1) * 128;
    const int t   = threadIdx.x;

    __shared__ float Bs[32][260];
    __shared__ float invL[2][32];
    __shared__ float wred[8];

    const int jg = t >> 4;
    const int p  = t & 15;
    const int h4 = t & 63;
    const int c  = t >> 6;    // wave-uniform

    const float* aArow0 = aA + (b * Nn + i0) * Hn;
    const float* aArow1 = aArow0 + Hn;

    float4 As0[4], As1[4];
#pragma unroll
    for (int r = 0; r < 4; ++r) {
        As0[r] = *reinterpret_cast<const float4*>(aArow0 + 4 * (p + 16 * r));
        As1[r] = *reinterpret_cast<const float4*>(aArow1 + 4 * (p + 16 * r));
    }
    const float4 a0 = *reinterpret_cast<const float4*>(aArow0 + h4 * 4);
    const float4 a1 = *reinterpret_cast<const float4*>(aArow1 + h4 * 4);

    const float* browbase = bB + b * Nn * Hn;

    float4 acc0 = make_float4(0.f, 0.f, 0.f, 0.f);
    float4 acc1 = make_float4(0.f, 0.f, 0.f, 0.f);
    float Csum = 0.f;

    float4 bv[4], bvn[4];
    {
        const float* rp = browbase + (jbase + jg) * Hn;
#pragma unroll
        for (int r = 0; r < 4; ++r)
            bv[r] = *reinterpret_cast<const float4*>(rp + 4 * (p + 16 * r));
    }

    for (int jt = 0; jt < 4; ++jt) {
        // ---- stats from staging registers ----
        float s0 = 0.f, q0 = 0.f, s1 = 0.f, q1 = 0.f;
#pragma unroll
        for (int r = 0; r < 4; ++r) {
            float v;
            v = fmaxf(As0[r].x + bv[r].x, 0.f); s0 += v; q0 = fmaf(v, v, q0);
            v = fmaxf(As0[r].y + bv[r].y, 0.f); s0 += v; q0 = fmaf(v, v, q0);
            v = fmaxf(As0[r].z + bv[r].z, 0.f); s0 += v; q0 = fmaf(v, v, q0);
            v = fmaxf(As0[r].w + bv[r].w, 0.f); s0 += v; q0 = fmaf(v, v, q0);
            v = fmaxf(As1[r].x + bv[r].x, 0.f); s1 += v; q1 = fmaf(v, v, q1);
            v = fmaxf(As1[r].y + bv[r].y, 0.f); s1 += v; q1 = fmaf(v, v, q1);
            v = fmaxf(As1[r].z + bv[r].z, 0.f); s1 += v; q1 = fmaf(v, v, q1);
            v = fmaxf(As1[r].w + bv[r].w, 0.f); s1 += v; q1 = fmaf(v, v, q1);
        }
        // ---- stage to LDS ----
#pragma unroll
        for (int r = 0; r < 4; ++r)
            *reinterpret_cast<float4*>(&Bs[jg][4 * (p + 16 * r)]) = bv[r];
        // ---- prefetch next tile ----
        if (jt < 3) {
            const float* rp = browbase + (jbase + (jt + 1) * 32 + jg) * Hn;
#pragma unroll
            for (int r = 0; r < 4; ++r)
                bvn[r] = *reinterpret_cast<const float4*>(rp + 4 * (p + 16 * r));
        }
        // ---- 16-lane reduce -> inv ----
#pragma unroll
        for (int off = 8; off >= 1; off >>= 1) {
            s0 += __shfl_xor(s0, off, 16);
            q0 += __shfl_xor(q0, off, 16);
            s1 += __shfl_xor(s1, off, 16);
            q1 += __shfl_xor(q1, off, 16);
        }
        if (p == 0) {
            float m0 = s0 * (1.f / 256.f), m1 = s1 * (1.f / 256.f);
            float inv0 = rsqrtf(q0 * (1.f / 256.f) - m0 * m0 + LN_EPS);
            float inv1 = rsqrtf(q1 * (1.f / 256.f) - m1 * m1 + LN_EPS);
            invL[0][jg] = inv0;
            invL[1][jg] = inv1;
            Csum -= m0 * inv0 + m1 * inv1;
        }
        __syncthreads();
        // ---- phase 2: weighted accumulate from LDS ----
#pragma unroll
        for (int jj = 0; jj < 4; ++jj) {
            int j = c * 4 + jj;
            float w0 = invL[0][j];
            float w1 = invL[1][j];
            float4 b4 = *reinterpret_cast<const float4*>(&Bs[j][h4 * 4]);
            acc0.x = fmaf(w0, fmaxf(a0.x + b4.x, 0.f), acc0.x);
            acc0.y = fmaf(w0, fmaxf(a0.y + b4.y, 0.f), acc0.y);
            acc0.z = fmaf(w0, fmaxf(a0.z + b4.z, 0.f), acc0.z);
            acc0.w = fmaf(w0, fmaxf(a0.w + b4.w, 0.f), acc0.w);
            acc1.x = fmaf(w1, fmaxf(a1.x + b4.x, 0.f), acc1.x);
            acc1.y = fmaf(w1, fmaxf(a1.y + b4.y, 0.f), acc1.y);
            acc1.z = fmaf(w1, fmaxf(a1.z + b4.z, 0.f), acc1.z);
            acc1.w = fmaf(w1, fmaxf(a1.w + b4.w, 0.f), acc1.w);
        }
        __syncthreads();
#pragma unroll
        for (int r = 0; r < 4; ++r) bv[r] = bvn[r];
    }

    // ---- combine: red aliases Bs (all phase-2 reads done) ----
    float* red = &Bs[0][0];   // red[(i*8+c)*256 + h]
    *reinterpret_cast<float4*>(red + c * 256 + h4 * 4) = acc0;
    *reinterpret_cast<float4*>(red + (8 + c) * 256 + h4 * 4) = acc1;

    float cs = Csum;
#pragma unroll
    for (int off = 32; off >= 1; off >>= 1) cs += __shfl_xor(cs, off, 64);
    if ((t & 63) == 0) wred[t >> 6] = cs;
    __syncthreads();

    if (t < 256) {
        float v = 0.f;
#pragma unroll
        for (int cc = 0; cc < 8; ++cc)
            v += red[cc * 256 + t] + red[(8 + cc) * 256 + t];
        atomicAdd(&rC[b * Hn + t], v);
    }
    if (t == 0) {
        float cb = 0.f;
#pragma unroll
        for (int w = 0; w < 8; ++w) cb += wred[w];
        Cpart[blockIdx.x] = cb;
    }
}

// ---------------------------------------------------------------------------
// Kernel 3: per-batch finish. 4 blocks x 1024 threads.
//   Cb = sum of 256 Cpart; rs[h] = gg[h]*(r[b,h]+Cb) + N^2*gb[h]
//   y = relu(rs@Wf + bf); rel = LN(y) (divisor 256)
// ---------------------------------------------------------------------------
__global__ __launch_bounds__(1024) void finish_kernel(
    const float* __restrict__ rC, const float* __restrict__ Cpart,
    const float* __restrict__ gg, const float* __restrict__ gb,
    const float* __restrict__ Wf, const float* __restrict__ bfv,
    const float* __restrict__ fg, const float* __restrict__ fb,
    float* __restrict__ rel)
{
    const int b = blockIdx.x;
    const int t = threadIdx.x;
    __shared__ float rs[256];
    __shared__ float ysum[16][260];
    __shared__ float cred[4];
    __shared__ float pS[4], pQ[4];

    float cv = (t < 256) ? Cpart[b * 256 + t] : 0.f;
#pragma unroll
    for (int off = 32; off >= 1; off >>= 1) cv += __shfl_xor(cv, off, 64);
    if (t < 256 && (t & 63) == 0) cred[t >> 6] = cv;
    __syncthreads();

    if (t < 256) {
        float Cb = cred[0] + cred[1] + cred[2] + cred[3];
        rs[t] = gg[t] * (rC[b * Hn + t] + Cb) + 65536.0f * gb[t];
    }
    __syncthreads();

    const int h4 = t & 63;
    const int kc = t >> 6;   // 0..15, 16 k each
    float4 acc = make_float4(0.f, 0.f, 0.f, 0.f);
    const float* Wp = Wf + h4 * 4;
#pragma unroll 8
    for (int kk = 0; kk < 16; ++kk) {
        int k = kc * 16 + kk;
        float4 w = *reinterpret_cast<const float4*>(Wp + k * Hn);
        float rv = rs[k];
        acc.x = fmaf(rv, w.x, acc.x);
        acc.y = fmaf(rv, w.y, acc.y);
        acc.z = fmaf(rv, w.z, acc.z);
        acc.w = fmaf(rv, w.w, acc.w);
    }
    *reinterpret_cast<float4*>(&ysum[kc][h4 * 4]) = acc;
    __syncthreads();

    float v = 0.f;
    if (t < 256) {
        v = bfv[t];
#pragma unroll
        for (int c = 0; c < 16; ++c) v += ysum[c][t];
        v = fmaxf(v, 0.f);
    }
    float sv = (t < 256) ? v : 0.f;
    float qv = (t < 256) ? v * v : 0.f;
#pragma unroll
    for (int off = 32; off >= 1; off >>= 1) {
        sv += __shfl_xor(sv, off, 64);
        qv += __shfl_xor(qv, off, 64);
    }
    if (t < 256 && (t & 63) == 0) { pS[t >> 6] = sv; pQ[t >> 6] = qv; }
    __syncthreads();

    if (t < 256) {
        float S = pS[0] + pS[1] + pS[2] + pS[3];
        float Q = pQ[0] + pQ[1] + pQ[2] + pQ[3];
        float m = S * (1.f / 256.f);
        float inv = rsqrtf(Q * (1.f / 256.f) - m * m + LN_EPS);
        rel[b * Hn + t] = (v - m) * inv * fg[t] + fb[t];
    }
}

// ---------------------------------------------------------------------------
// Kernel 4: out[b,n,d] = rel[b,d] + x[b,n,d], float4-vectorized.
// ---------------------------------------------------------------------------
__global__ __launch_bounds__(256) void add_kernel(
    const float* __restrict__ rel, const float* __restrict__ x,
    float* __restrict__ out)
{
    int idx = blockIdx.x * blockDim.x + threadIdx.x;   // float4 units
    int b = idx >> 14;
    int d4 = idx & 63;
    float4 r4 = reinterpret_cast<const float4*>(rel)[b * 64 + d4];
    float4 x4 = reinterpret_cast<const float4*>(x)[idx];
    float4 o;
    o.x = r4.x + x4.x;
    o.y = r4.y + x4.y;
    o.z = r4.z + x4.z;
    o.w = r4.w + x4.w;
    reinterpret_cast<float4*>(out)[idx] = o;
}

// ---------------------------------------------------------------------------
extern "C" void kernel_launch(void* const* d_in, const int* in_sizes, int n_in,
                              void* d_out, int out_size, void* d_ws, size_t ws_size,
                              hipStream_t stream)
{
    const float* x   = (const float*)d_in[0];
    const float* Wg  = (const float*)d_in[1];
    const float* bg  = (const float*)d_in[2];
    const float* gg  = (const float*)d_in[3];
    const float* gb  = (const float*)d_in[4];
    const float* Wf  = (const float*)d_in[5];
    const float* bfv = (const float*)d_in[6];
    const float* fg  = (const float*)d_in[7];
    const float* fb  = (const float*)d_in[8];
    float* out = (float*)d_out;

    float* ws    = (float*)d_ws;
    float* aA    = ws;                 // 1024*256
    float* bB    = ws + 262144;        // 1024*256
    float* rC    = ws + 524288;        // 1024
    float* Cpart = ws + 525312;        // 1024
    float* rel   = ws + 526336;        // 1024

    gemm_ab_kernel<<<dim3(256, 2), 512, 0, stream>>>(x, Wg, bg, aA, bB, rC);
    pair_kernel<<<1024, 512, 0, stream>>>(aA, bB, rC, Cpart);
    finish_kernel<<<4, 1024, 0, stream>>>(rC, Cpart, gg, gb, Wf, bfv, fg, fb, rel);
    add_kernel<<<256, 256, 0, stream>>>(rel, x, out);
}

// Round 6
// 103.177 us; speedup vs baseline: 1.1410x; 1.1410x over previous
//
#include <hip/hip_runtime.h>

#define LN_EPS 1e-5f

constexpr int Bn = 4, Nn = 256, Dn = 256, Hn = 256;

// ws layout (floats):
//   aA    @ 0        (1024*256)
//   bB    @ 262144   (1024*256)
//   rC    @ 524288   (1024)      -- atomic accumulators r[b,h], zeroed in gemm
//   Cpart @ 525312   (512)       -- per-pair-block C partials (no contention)
//   rel   @ 525824   (1024)

// ---------------------------------------------------------------------------
// Kernel 1: aA[m,h] = x[m,:]@Wg[:D,h] + bg[h]  (half=0)
//           bB[m,h] = x[m,:]@Wg[D:,h]          (half=1)
// Block: 4-row m-tile, 512 threads = (h4 in [0,64), dc in [0,8)).
// float4 W loads (1KB/wave coalesced). Block (0,0) zeroes rC.
// ---------------------------------------------------------------------------
__global__ __launch_bounds__(512) void gemm_ab_kernel(
    const float* __restrict__ x, const float* __restrict__ Wg,
    const float* __restrict__ bg, float* __restrict__ aA,
    float* __restrict__ bB, float* __restrict__ rC)
{
    int mt = blockIdx.x;     // 0..255
    int half = blockIdx.y;   // 0 -> a, 1 -> b
    int m0 = mt * 4;
    int t = threadIdx.x;

    if (mt == 0 && half == 0) {
        for (int k = t; k < 1024; k += 512) rC[k] = 0.0f;
    }

    __shared__ float xs[4][256];
    __shared__ float accP[8][4][256];

    if (t < 256)
        reinterpret_cast<float4*>(&xs[0][0])[t] =
            reinterpret_cast<const float4*>(x + m0 * Dn)[t];
    __syncthreads();

    int h4 = t & 63;
    int dc = t >> 6;         // wave-uniform
    const float* Wp = Wg + (half ? Dn * Hn : 0) + h4 * 4;

    float4 acc[4];
#pragma unroll
    for (int m = 0; m < 4; ++m) acc[m] = make_float4(0.f, 0.f, 0.f, 0.f);

#pragma unroll 4
    for (int dd = 0; dd < 32; ++dd) {
        int d = dc * 32 + dd;
        float4 w = *reinterpret_cast<const float4*>(Wp + d * Hn);
#pragma unroll
        for (int m = 0; m < 4; ++m) {
            float xv = xs[m][d];
            acc[m].x = fmaf(xv, w.x, acc[m].x);
            acc[m].y = fmaf(xv, w.y, acc[m].y);
            acc[m].z = fmaf(xv, w.z, acc[m].z);
            acc[m].w = fmaf(xv, w.w, acc[m].w);
        }
    }
#pragma unroll
    for (int m = 0; m < 4; ++m)
        *reinterpret_cast<float4*>(&accP[dc][m][h4 * 4]) = acc[m];
    __syncthreads();

    int h = t & 255;
    int mh = t >> 8;
    float binit = half ? 0.0f : bg[h];
    float* outp = half ? bB : aA;
#pragma unroll
    for (int mi = 0; mi < 2; ++mi) {
        int m = mh * 2 + mi;
        float v = binit;
#pragma unroll
        for (int c = 0; c < 8; ++c) v += accP[c][m][h];
        outp[(m0 + m) * Hn + h] = v;
    }
}

// ---------------------------------------------------------------------------
// Kernel 2: fused pair block, SINGLE pass over bB.
// Block = (b, 2 i-rows), 512 threads, grid 512 (2 blocks/CU).
// __launch_bounds__(512, 2): <=128 VGPR, ~100 live registers fit SPILL-FREE
// (the previous (512,4) capped at 64 VGPR and spilled ~40 regs to scratch
// inside the j-tile loop -- the dominant cost of this kernel).
// Per j-tile (32 rows, 32KB):
//   stage: thread (jg=t>>4, p=t&15) loads row jg cols {p+16r}r<4 as float4,
//          computes LN stats from the SAME registers, ds_writes to Bs,
//          prefetches next tile, 16-lane shuffle reduce -> invL[i][jg].
//   phase2: thread (h4=t&63, c=t>>6) accumulates over its 4 j's from LDS.
// End: LDS combine (red aliases Bs), 1 atomic/h; Cpart[block] (no contention).
// ---------------------------------------------------------------------------
__global__ __launch_bounds__(512, 2) void pair_kernel(
    const float* __restrict__ aA, const float* __restrict__ bB,
    float* __restrict__ rC, float* __restrict__ Cpart)
{
    const int b  = blockIdx.x >> 7;
    const int i0 = (blockIdx.x & 127) * 2;
    const int t  = threadIdx.x;

    __shared__ float Bs[32][260];
    __shared__ float invL[2][32];
    __shared__ float wred[8];

    const int jg = t >> 4;
    const int p  = t & 15;
    const int h4 = t & 63;
    const int c  = t >> 6;    // wave-uniform

    const float* aArow0 = aA + (b * Nn + i0) * Hn;
    const float* aArow1 = aArow0 + Hn;

    // stats-mapping A fragments: h = 4*(p+16r)+{0..3}
    float4 As0[4], As1[4];
#pragma unroll
    for (int r = 0; r < 4; ++r) {
        As0[r] = *reinterpret_cast<const float4*>(aArow0 + 4 * (p + 16 * r));
        As1[r] = *reinterpret_cast<const float4*>(aArow1 + 4 * (p + 16 * r));
    }
    // phase2-mapping A fragments: h = h4*4+{0..3}
    const float4 a0 = *reinterpret_cast<const float4*>(aArow0 + h4 * 4);
    const float4 a1 = *reinterpret_cast<const float4*>(aArow1 + h4 * 4);

    const float* browbase = bB + b * Nn * Hn;

    float4 acc0 = make_float4(0.f, 0.f, 0.f, 0.f);
    float4 acc1 = make_float4(0.f, 0.f, 0.f, 0.f);
    float Csum = 0.f;

    float4 bv[4], bvn[4];
    {
        const float* rp = browbase + jg * Hn;
#pragma unroll
        for (int r = 0; r < 4; ++r)
            bv[r] = *reinterpret_cast<const float4*>(rp + 4 * (p + 16 * r));
    }

    for (int jt = 0; jt < 8; ++jt) {
        // ---- stats from staging registers ----
        float s0 = 0.f, q0 = 0.f, s1 = 0.f, q1 = 0.f;
#pragma unroll
        for (int r = 0; r < 4; ++r) {
            float v;
            v = fmaxf(As0[r].x + bv[r].x, 0.f); s0 += v; q0 = fmaf(v, v, q0);
            v = fmaxf(As0[r].y + bv[r].y, 0.f); s0 += v; q0 = fmaf(v, v, q0);
            v = fmaxf(As0[r].z + bv[r].z, 0.f); s0 += v; q0 = fmaf(v, v, q0);
            v = fmaxf(As0[r].w + bv[r].w, 0.f); s0 += v; q0 = fmaf(v, v, q0);
            v = fmaxf(As1[r].x + bv[r].x, 0.f); s1 += v; q1 = fmaf(v, v, q1);
            v = fmaxf(As1[r].y + bv[r].y, 0.f); s1 += v; q1 = fmaf(v, v, q1);
            v = fmaxf(As1[r].z + bv[r].z, 0.f); s1 += v; q1 = fmaf(v, v, q1);
            v = fmaxf(As1[r].w + bv[r].w, 0.f); s1 += v; q1 = fmaf(v, v, q1);
        }
        // ---- stage to LDS ----
#pragma unroll
        for (int r = 0; r < 4; ++r)
            *reinterpret_cast<float4*>(&Bs[jg][4 * (p + 16 * r)]) = bv[r];
        // ---- prefetch next tile ----
        if (jt < 7) {
            const float* rp = browbase + ((jt + 1) * 32 + jg) * Hn;
#pragma unroll
            for (int r = 0; r < 4; ++r)
                bvn[r] = *reinterpret_cast<const float4*>(rp + 4 * (p + 16 * r));
        }
        // ---- 16-lane reduce -> inv ----
#pragma unroll
        for (int off = 8; off >= 1; off >>= 1) {
            s0 += __shfl_xor(s0, off, 16);
            q0 += __shfl_xor(q0, off, 16);
            s1 += __shfl_xor(s1, off, 16);
            q1 += __shfl_xor(q1, off, 16);
        }
        if (p == 0) {
            float m0 = s0 * (1.f / 256.f), m1 = s1 * (1.f / 256.f);
            float inv0 = rsqrtf(q0 * (1.f / 256.f) - m0 * m0 + LN_EPS);
            float inv1 = rsqrtf(q1 * (1.f / 256.f) - m1 * m1 + LN_EPS);
            invL[0][jg] = inv0;
            invL[1][jg] = inv1;
            Csum -= m0 * inv0 + m1 * inv1;
        }
        __syncthreads();
        // ---- phase 2: weighted accumulate from LDS ----
#pragma unroll
        for (int jj = 0; jj < 4; ++jj) {
            int j = c * 4 + jj;
            float w0 = invL[0][j];
            float w1 = invL[1][j];
            float4 b4 = *reinterpret_cast<const float4*>(&Bs[j][h4 * 4]);
            acc0.x = fmaf(w0, fmaxf(a0.x + b4.x, 0.f), acc0.x);
            acc0.y = fmaf(w0, fmaxf(a0.y + b4.y, 0.f), acc0.y);
            acc0.z = fmaf(w0, fmaxf(a0.z + b4.z, 0.f), acc0.z);
            acc0.w = fmaf(w0, fmaxf(a0.w + b4.w, 0.f), acc0.w);
            acc1.x = fmaf(w1, fmaxf(a1.x + b4.x, 0.f), acc1.x);
            acc1.y = fmaf(w1, fmaxf(a1.y + b4.y, 0.f), acc1.y);
            acc1.z = fmaf(w1, fmaxf(a1.z + b4.z, 0.f), acc1.z);
            acc1.w = fmaf(w1, fmaxf(a1.w + b4.w, 0.f), acc1.w);
        }
        __syncthreads();
#pragma unroll
        for (int r = 0; r < 4; ++r) bv[r] = bvn[r];
    }

    // ---- combine: red aliases Bs (all phase-2 reads done) ----
    float* red = &Bs[0][0];   // red[(i*8+c)*256 + h], 4096 floats
    *reinterpret_cast<float4*>(red + c * 256 + h4 * 4) = acc0;
    *reinterpret_cast<float4*>(red + (8 + c) * 256 + h4 * 4) = acc1;

    float cs = Csum;
#pragma unroll
    for (int off = 32; off >= 1; off >>= 1) cs += __shfl_xor(cs, off, 64);
    if ((t & 63) == 0) wred[t >> 6] = cs;
    __syncthreads();

    if (t < 256) {
        float v = 0.f;
#pragma unroll
        for (int cc = 0; cc < 8; ++cc)
            v += red[cc * 256 + t] + red[(8 + cc) * 256 + t];
        atomicAdd(&rC[b * Hn + t], v);
    }
    if (t == 0) {
        float cb = 0.f;
#pragma unroll
        for (int w = 0; w < 8; ++w) cb += wred[w];
        Cpart[blockIdx.x] = cb;
    }
}

// ---------------------------------------------------------------------------
// Kernel 3: per-batch finish. 4 blocks x 512 threads.
//   Cb = sum of 128 Cpart; rs[h] = gg[h]*(r[b,h]+Cb) + N^2*gb[h]
//   y = relu(rs@Wf + bf); rel = LN(y) (divisor 256)
// ---------------------------------------------------------------------------
__global__ __launch_bounds__(512) void finish_kernel(
    const float* __restrict__ rC, const float* __restrict__ Cpart,
    const float* __restrict__ gg, const float* __restrict__ gb,
    const float* __restrict__ Wf, const float* __restrict__ bfv,
    const float* __restrict__ fg, const float* __restrict__ fb,
    float* __restrict__ rel)
{
    const int b = blockIdx.x;
    const int t = threadIdx.x;
    __shared__ float rs[256];
    __shared__ float ysum[8][260];
    __shared__ float cred[2];
    __shared__ float pS[4], pQ[4];

    float cv = (t < 128) ? Cpart[b * 128 + t] : 0.f;
#pragma unroll
    for (int off = 32; off >= 1; off >>= 1) cv += __shfl_xor(cv, off, 64);
    if (t == 0 || t == 64) cred[t >> 6] = cv;
    __syncthreads();

    if (t < 256) {
        float Cb = cred[0] + cred[1];
        rs[t] = gg[t] * (rC[b * Hn + t] + Cb) + 65536.0f * gb[t];
    }
    __syncthreads();

    const int h4 = t & 63;
    const int kc = t >> 6;   // 0..7, 32 k each
    float4 acc = make_float4(0.f, 0.f, 0.f, 0.f);
    const float* Wp = Wf + h4 * 4;
#pragma unroll 8
    for (int kk = 0; kk < 32; ++kk) {
        int k = kc * 32 + kk;
        float4 w = *reinterpret_cast<const float4*>(Wp + k * Hn);
        float rv = rs[k];
        acc.x = fmaf(rv, w.x, acc.x);
        acc.y = fmaf(rv, w.y, acc.y);
        acc.z = fmaf(rv, w.z, acc.z);
        acc.w = fmaf(rv, w.w, acc.w);
    }
    *reinterpret_cast<float4*>(&ysum[kc][h4 * 4]) = acc;
    __syncthreads();

    float v = 0.f;
    if (t < 256) {
        v = bfv[t];
#pragma unroll
        for (int c = 0; c < 8; ++c) v += ysum[c][t];
        v = fmaxf(v, 0.f);
    }
    float sv = (t < 256) ? v : 0.f;
    float qv = (t < 256) ? v * v : 0.f;
#pragma unroll
    for (int off = 32; off >= 1; off >>= 1) {
        sv += __shfl_xor(sv, off, 64);
        qv += __shfl_xor(qv, off, 64);
    }
    if (t < 256 && (t & 63) == 0) { pS[t >> 6] = sv; pQ[t >> 6] = qv; }
    __syncthreads();

    if (t < 256) {
        float S = pS[0] + pS[1] + pS[2] + pS[3];
        float Q = pQ[0] + pQ[1] + pQ[2] + pQ[3];
        float m = S * (1.f / 256.f);
        float inv = rsqrtf(Q * (1.f / 256.f) - m * m + LN_EPS);
        rel[b * Hn + t] = (v - m) * inv * fg[t] + fb[t];
    }
}

// ---------------------------------------------------------------------------
// Kernel 4: out[b,n,d] = rel[b,d] + x[b,n,d], float4-vectorized.
// ---------------------------------------------------------------------------
__global__ __launch_bounds__(256) void add_kernel(
    const float* __restrict__ rel, const float* __restrict__ x,
    float* __restrict__ out)
{
    int idx = blockIdx.x * blockDim.x + threadIdx.x;   // float4 units
    int b = idx >> 14;
    int d4 = idx & 63;
    float4 r4 = reinterpret_cast<const float4*>(rel)[b * 64 + d4];
    float4 x4 = reinterpret_cast<const float4*>(x)[idx];
    float4 o;
    o.x = r4.x + x4.x;
    o.y = r4.y + x4.y;
    o.z = r4.z + x4.z;
    o.w = r4.w + x4.w;
    reinterpret_cast<float4*>(out)[idx] = o;
}

// ---------------------------------------------------------------------------
extern "C" void kernel_launch(void* const* d_in, const int* in_sizes, int n_in,
                              void* d_out, int out_size, void* d_ws, size_t ws_size,
                              hipStream_t stream)
{
    const float* x   = (const float*)d_in[0];
    const float* Wg  = (const float*)d_in[1];
    const float* bg  = (const float*)d_in[2];
    const float* gg  = (const float*)d_in[3];
    const float* gb  = (const float*)d_in[4];
    const float* Wf  = (const float*)d_in[5];
    const float* bfv = (const float*)d_in[6];
    const float* fg  = (const float*)d_in[7];
    const float* fb  = (const float*)d_in[8];
    float* out = (float*)d_out;

    float* ws    = (float*)d_ws;
    float* aA    = ws;                 // 1024*256
    float* bB    = ws + 262144;        // 1024*256
    float* rC    = ws + 524288;        // 1024
    float* Cpart = ws + 525312;        // 512
    float* rel   = ws + 525824;        // 1024

    gemm_ab_kernel<<<dim3(256, 2), 512, 0, stream>>>(x, Wg, bg, aA, bB, rC);
    pair_kernel<<<512, 512, 0, stream>>>(aA, bB, rC, Cpart);
    finish_kernel<<<4, 512, 0, stream>>>(rC, Cpart, gg, gb, Wf, bfv, fg, fb, rel);
    add_kernel<<<256, 256, 0, stream>>>(rel, x, out);
}